// Round 13
// baseline (262.538 us; speedup 1.0000x reference)
//
#include <hip/hip_runtime.h>
#include <hip/hip_bf16.h>
#include <math.h>

#define BB   1024
#define NN   256
#define FF   64
#define FSS  128
#define OUTT 128
#define SS   4
#define HH   4
#define KK   4
#define HDD  16
#define EPSF 1e-5f
#define BIGF 1000000000.0f
#define ROWB 72
#define ROWA 68

typedef __attribute__((ext_vector_type(8))) short short8;
typedef __attribute__((ext_vector_type(4))) float f32x4;

static __device__ __forceinline__ unsigned short f2bf(float f) {
  union { float f; unsigned u; } x; x.f = f;
  unsigned u = x.u + 0x7fffu + ((x.u >> 16) & 1u);   // RNE
  return (unsigned short)(u >> 16);
}
static __device__ __forceinline__ float bf2f(unsigned short h) {
  union { unsigned u; float f; } x; x.u = ((unsigned)h) << 16;
  return x.f;
}
static __device__ __forceinline__ float bflo(unsigned u) {
  union { unsigned u; float f; } x; x.u = u << 16; return x.f;
}
static __device__ __forceinline__ float bfhi(unsigned u) {
  union { unsigned u; float f; } x; x.u = u & 0xffff0000u; return x.f;
}
static __device__ __forceinline__ unsigned pack2(float a, float b) {
  return (unsigned)f2bf(a) | ((unsigned)f2bf(b) << 16);
}

// ---------------------------------------------------------------- k_prep: fold q through wk
__global__ __launch_bounds__(256) void k_prep(
    const float* __restrict__ sq, const float* __restrict__ wq, const float* __restrict__ bq,
    const float* __restrict__ wk, const float* __restrict__ bk,
    float* __restrict__ V_o, float* __restrict__ c_o)
{
  const int tid = threadIdx.x;
  __shared__ float sq_s[SS*FF];
  __shared__ float q_s[SS*FF];
  sq_s[tid] = sq[tid];
  __syncthreads();
  {
    int s = tid >> 6, f = tid & 63;
    float acc = bq[f];
    for (int c = 0; c < FF; ++c) acc += sq_s[s*FF+c] * wq[c*FF+f];
    q_s[s*FF+f] = acc;
  }
  __syncthreads();
  {
    int c = tid & 63, jb = (tid >> 6) * 4;
    for (int jj = 0; jj < 4; ++jj) {
      int j = jb + jj, h = j >> 2, s = j & 3;
      float acc = 0.f;
      for (int d = 0; d < HDD; ++d)
        acc += wk[c*FF + h*HDD + d] * q_s[s*FF + h*HDD + d];
      V_o[c*16 + j] = acc * 0.25f;
    }
  }
  if (tid < 16) {
    int h = tid >> 2, s = tid & 3;
    float acc = 0.f;
    for (int d = 0; d < HDD; ++d) acc += bk[h*HDD+d] * q_s[s*FF + h*HDD + d];
    c_o[tid] = acc * 0.25f;
  }
}

// ---------------------------------------------------------------- K1: attention + assign + sf
__global__ __launch_bounds__(256, 3) void k_attn_sf(
    const float* __restrict__ axle,
    const float* __restrict__ Vm, const float* __restrict__ cv,
    const float* __restrict__ w_a2s, const float* __restrict__ b_a2s,
    float* __restrict__ assign_o, float* __restrict__ sf_o)
{
  const int b = blockIdx.x, tid = threadIdx.x;
  const int wv = tid >> 6, ln = tid & 63;
  __shared__ __align__(16) unsigned short xb_a[NN*ROWA];
  __shared__ __align__(16) unsigned char u_buf[16*NN*2];
  __shared__ float mz_s[16][2];
  __hip_bfloat16* sc_s = (__hip_bfloat16*)u_buf;
  float (*as_s)[SS]    = (float (*)[SS])u_buf;
  float* t_s           = (float*)(u_buf + 4096);
  float* As_s          = (float*)(u_buf + 4096 + 1024);

  const float* afb = axle + (size_t)b*NN*FF;
  const float4* in4 = reinterpret_cast<const float4*>(afb);
  for (int i4 = tid; i4 < NN*FF/4; i4 += 256) {
    float4 v = in4[i4];
    int n = i4 >> 4, c4 = (i4 & 15) * 4;
    uint2 pk; pk.x = pack2(v.x, v.y); pk.y = pack2(v.z, v.w);
    *reinterpret_cast<uint2*>(&xb_a[n*ROWA + c4]) = pk;
  }
  __syncthreads();

  {
    float sc[16];
    #pragma unroll
    for (int j = 0; j < 16; ++j) sc[j] = cv[j];
    #pragma unroll
    for (int k = 0; k < 16; ++k) {
      uint2 pk = *reinterpret_cast<const uint2*>(&xb_a[tid*ROWA + 4*k]);
      float x0 = bflo(pk.x), x1 = bfhi(pk.x), x2 = bflo(pk.y), x3 = bfhi(pk.y);
      #pragma unroll
      for (int j = 0; j < 16; ++j) {
        float a = fmaf(x0, Vm[(4*k+0)*16+j], sc[j]);
        a = fmaf(x1, Vm[(4*k+1)*16+j], a);
        a = fmaf(x2, Vm[(4*k+2)*16+j], a);
        sc[j] = fmaf(x3, Vm[(4*k+3)*16+j], a);
      }
    }
    #pragma unroll
    for (int j = 0; j < 16; ++j) sc_s[j*NN + tid] = __float2bfloat16(sc[j]);
  }
  __syncthreads();

  for (int r = 0; r < 4; ++r) {
    int row = wv*4 + r;
    float v0 = __bfloat162float(sc_s[row*NN + ln]);
    float v1 = __bfloat162float(sc_s[row*NN + ln + 64]);
    float v2 = __bfloat162float(sc_s[row*NN + ln + 128]);
    float v3 = __bfloat162float(sc_s[row*NN + ln + 192]);
    float m = fmaxf(fmaxf(v0,v1), fmaxf(v2,v3));
    #pragma unroll
    for (int o = 32; o; o >>= 1) m = fmaxf(m, __shfl_xor(m, o));
    float z = __expf(v0-m) + __expf(v1-m) + __expf(v2-m) + __expf(v3-m);
    #pragma unroll
    for (int o = 32; o; o >>= 1) z += __shfl_xor(z, o);
    if (ln == 0) { mz_s[row][0] = m; mz_s[row][1] = 1.f/z; }
  }
  __syncthreads();

  float4 av;
  {
    float at0 = 0.f, at1 = 0.f, at2 = 0.f, at3 = 0.f;
    #pragma unroll
    for (int h = 0; h < HH; ++h) {
      at0 += __expf(__bfloat162float(sc_s[(h*4+0)*NN + tid]) - mz_s[h*4+0][0]) * mz_s[h*4+0][1];
      at1 += __expf(__bfloat162float(sc_s[(h*4+1)*NN + tid]) - mz_s[h*4+1][0]) * mz_s[h*4+1][1];
      at2 += __expf(__bfloat162float(sc_s[(h*4+2)*NN + tid]) - mz_s[h*4+2][0]) * mz_s[h*4+2][1];
      at3 += __expf(__bfloat162float(sc_s[(h*4+3)*NN + tid]) - mz_s[h*4+3][0]) * mz_s[h*4+3][1];
    }
    at0 *= 0.25f; at1 *= 0.25f; at2 *= 0.25f; at3 *= 0.25f;
    float m = fmaxf(fmaxf(at0,at1), fmaxf(at2,at3));
    float e0=__expf(at0-m), e1=__expf(at1-m), e2=__expf(at2-m), e3=__expf(at3-m);
    float zi = 1.f/(e0+e1+e2+e3);
    av = make_float4(e0*zi, e1*zi, e2*zi, e3*zi);
    reinterpret_cast<float4*>(assign_o)[(size_t)b*NN + tid] = av;
  }
  __syncthreads();
  *reinterpret_cast<float4*>(&as_s[tid][0]) = av;
  __syncthreads();

  {
    int s = wv, half = ln >> 5, c2 = ln & 31;
    float t0 = 0.f, t1 = 0.f, aa = 0.f;
    int n0 = half * 128;
    for (int n = n0; n < n0 + 128; ++n) {
      float a = as_s[n][s];
      unsigned pk = *reinterpret_cast<const unsigned*>(&xb_a[n*ROWA + 2*c2]);
      t0 = fmaf(a, bflo(pk), t0);
      t1 = fmaf(a, bfhi(pk), t1);
      aa += a;
    }
    t0 += __shfl_xor(t0, 32);
    t1 += __shfl_xor(t1, 32);
    aa += __shfl_xor(aa, 32);
    if (half == 0) {
      t_s[s*FF + 2*c2]     = t0;
      t_s[s*FF + 2*c2 + 1] = t1;
      if (c2 == 0) As_s[s] = aa;
    }
  }
  __syncthreads();

  for (int o = tid; o < SS*FSS; o += 256) {
    int s = o >> 7, f = o & 127;
    float acc = As_s[s] * b_a2s[f];
    for (int c = 0; c < FF; ++c) acc += t_s[s*FF + c] * w_a2s[c*FSS+f];
    sf_o[((size_t)b*SS+s)*FSS+f] = acc;
  }
}

// ---------------------------------------------------------------- coarse graph conv (packed coalesced stats)
__global__ __launch_bounds__(128) void k_coarse(
    const float* __restrict__ in, const float* __restrict__ W, const float* __restrict__ bias,
    const float* __restrict__ pmu, const float* __restrict__ prstd,
    const float* __restrict__ pgamma, const float* __restrict__ pbeta, int applyBN,
    float* __restrict__ out, float2* __restrict__ stp)
{
  const int b = blockIdx.x, f = threadIdx.x;
  __shared__ float x_s[SS][FSS];
  #pragma unroll
  for (int i = 0; i < SS; ++i) {
    float v = in[((size_t)b*SS+i)*FSS + f];
    if (applyBN) v = fmaxf((v - pmu[f])*prstd[f]*pgamma[f] + pbeta[f], 0.f);
    x_s[i][f] = v;
  }
  __syncthreads();
  float h0 = bias[f], h1 = h0, h2 = h0, h3 = h0;
  for (int c = 0; c < FSS; ++c) {
    float w = W[c*FSS+f];
    h0 += x_s[0][c]*w; h1 += x_s[1][c]*w; h2 += x_s[2][c]*w; h3 += x_s[3][c]*w;
  }
  float s4 = h0+h1+h2+h3;
  const float inv3 = 1.f/3.f;
  float o0 = h0 + (s4-h0)*inv3;
  float o1 = h1 + (s4-h1)*inv3;
  float o2 = h2 + (s4-h2)*inv3;
  float o3 = h3 + (s4-h3)*inv3;
  size_t ob = (size_t)b*SS*FSS + f;
  out[ob] = o0; out[ob+FSS] = o1; out[ob+2*FSS] = o2; out[ob+3*FSS] = o3;
  stp[(size_t)b*FSS + f] = make_float2(o0+o1+o2+o3, o0*o0+o1*o1+o2*o2+o3*o3);
}

// ---------------------------------------------------------------- BN stats reduce (transposed packed reads)
__global__ __launch_bounds__(256) void k_bnstats(
    const float2* __restrict__ sp, float* __restrict__ mu, float* __restrict__ rstd,
    float invcnt, int F)
{
  const int f = blockIdx.x, tid = threadIdx.x;
  float a = 0.f, q = 0.f;
  for (int j = tid; j < BB; j += 256) {
    float2 v = sp[(size_t)j*F + f];
    a += v.x; q += v.y;
  }
  #pragma unroll
  for (int o = 32; o; o >>= 1) { a += __shfl_xor(a, o); q += __shfl_xor(q, o); }
  __shared__ float ra[4], rq[4];
  int wv = tid >> 6;
  if ((tid & 63) == 0) { ra[wv] = a; rq[wv] = q; }
  __syncthreads();
  if (tid == 0) {
    float s = ra[0]+ra[1]+ra[2]+ra[3], ss = rq[0]+rq[1]+rq[2]+rq[3];
    float m = s*invcnt; float v = ss*invcnt - m*m;
    mu[f] = m; rstd[f] = 1.f / sqrtf(v + EPSF);
  }
}

// ---------------------------------------------------------------- fused kNN + ctx (512 threads)
// axle prefetched into 32 VGPRs BEFORE the VALU-bound kNN scan -> HBM latency hidden.
__global__ __launch_bounds__(512) void k_knn_ctx(
    const float* __restrict__ pos, const float* __restrict__ pres,
    const float* __restrict__ axle, const float* __restrict__ hc1,
    const float* __restrict__ mu, const float* __restrict__ rstd,
    const float* __restrict__ gamma, const float* __restrict__ beta,
    const float* __restrict__ assign_i,
    const float* __restrict__ w_s2a, const float* __restrict__ b_s2a,
    int* __restrict__ rev_go, int* __restrict__ offs_go,
    float* __restrict__ ivd_o, unsigned short* __restrict__ af_o)
{
  const int b = blockIdx.x, tid = threadIdx.x;
  const int ln = tid & 63, wv = tid >> 6;
  const int n = tid >> 1, half = tid & 1;
  __shared__ float2 pp[NN];
  __shared__ int vld[NN];
  __shared__ int wcnt[4];
  __shared__ int wsum[4];
  __shared__ int nbr_s[NN*KK];
  __shared__ int cnti[NN], scn[NN], cur[NN];
  __shared__ __align__(16) int rev_s[NN*KK];
  __shared__ float csf[SS][FSS];
  __shared__ float u_s[SS][FF];

  // prefetch axle for ctx phase (independent of kNN): loads land during the scan
  const size_t gb = (size_t)b*NN*FF;
  const float4* ax4 = reinterpret_cast<const float4*>(axle + gb);
  float4 axr[8];
  #pragma unroll
  for (int r = 0; r < 8; ++r) axr[r] = ax4[tid + r*512];

  // ---------------- phase 1: kNN ----------------
  if (tid < NN) {
    float2 p = reinterpret_cast<const float2*>(pos)[(size_t)b*NN + tid];
    float pr = pres[(size_t)b*NN + tid];
    int v = pr > 0.5f ? 1 : 0;
    vld[tid] = v;
    pp[tid] = v ? p : make_float2(3.4e38f, 3.4e38f);
    cnti[tid] = 0; cur[tid] = 0;
    reinterpret_cast<int4*>(rev_s)[tid] = make_int4(0,0,0,0);
    int cnt = v;
    #pragma unroll
    for (int o = 32; o; o >>= 1) cnt += __shfl_xor(cnt, o);
    if (ln == 0) wcnt[wv] = cnt;
  }
  __syncthreads();
  const int nv = wcnt[0]+wcnt[1]+wcnt[2]+wcnt[3];

  float2 sp = pp[n];
  const float xi = sp.x, yi = sp.y;
  float b0=3.4e38f, b1=b0, b2=b0, b3=b0, b4=b0;
  int   j0=0, j1=0, j2=0, j3=0, j4=0;
  const int jb = half << 7;
  for (int j = jb; j < jb + 128; ++j) {
    float2 q = pp[j];
    float dx = __fsub_rn(xi, q.x);
    float dy = __fsub_rn(yi, q.y);
    float d2 = __fadd_rn(__fmul_rn(dx,dx), __fmul_rn(dy,dy)); // no fma: match numpy
    if (d2 < b4) {
      b4 = d2; j4 = j;
      if (b4 < b3) { float t=b3; b3=b4; b4=t; int ti=j3; j3=j4; j4=ti; }
      if (b3 < b2) { float t=b2; b2=b3; b3=t; int ti=j2; j2=j3; j3=ti; }
      if (b2 < b1) { float t=b1; b1=b2; b2=t; int ti=j1; j1=j2; j2=ti; }
      if (b1 < b0) { float t=b0; b0=b1; b1=t; int ti=j0; j0=j1; j1=ti; }
    }
  }
  float c0 = __shfl_xor(b0,1), c1 = __shfl_xor(b1,1), c2 = __shfl_xor(b2,1),
        c3 = __shfl_xor(b3,1), c4 = __shfl_xor(b4,1);
  int   k0 = __shfl_xor(j0,1), k1 = __shfl_xor(j1,1), k2 = __shfl_xor(j2,1),
        k3 = __shfl_xor(j3,1), k4 = __shfl_xor(j4,1);

  if (half == 0) {
#define MSTEP(OD, OJ) do { bool ta = (b0 <= c0); \
    OD = ta ? b0 : c0; OJ = ta ? j0 : k0; \
    b0 = ta ? b1 : b0; j0 = ta ? j1 : j0; \
    b1 = ta ? b2 : b1; j1 = ta ? j2 : j1; \
    b2 = ta ? b3 : b2; j2 = ta ? j3 : j2; \
    b3 = ta ? b4 : b3; j3 = ta ? j4 : j3; \
    b4 = ta ? 3.4e38f : b4; \
    c0 = ta ? c0 : c1; k0 = ta ? k0 : k1; \
    c1 = ta ? c1 : c2; k1 = ta ? k1 : k2; \
    c2 = ta ? c2 : c3; k2 = ta ? k2 : k3; \
    c3 = ta ? c3 : c4; k3 = ta ? k3 : k4; \
    c4 = ta ? c4 : 3.4e38f; } while(0)
    float m0d, dd1, dd2, dd3, dd4; int m0j, i1, i2, i3, i4;
    MSTEP(m0d, m0j);
    MSTEP(dd1, i1); MSTEP(dd2, i2); MSTEP(dd3, i3); MSTEP(dd4, i4);
#undef MSTEP
    (void)m0d; (void)m0j;
    bool okrow = (vld[n] != 0) && (nv >= 2);
    int e0 = (okrow && dd1 < 0.5f*BIGF) ? i1 : -1;
    int e1 = (okrow && dd2 < 0.5f*BIGF) ? i2 : -1;
    int e2 = (okrow && dd3 < 0.5f*BIGF) ? i3 : -1;
    int e3 = (okrow && dd4 < 0.5f*BIGF) ? i4 : -1;
    nbr_s[n*KK+0] = e0; nbr_s[n*KK+1] = e1;
    nbr_s[n*KK+2] = e2; nbr_s[n*KK+3] = e3;
    if (e0 >= 0) atomicAdd(&cnti[e0], 1);
    if (e1 >= 0) atomicAdd(&cnti[e1], 1);
    if (e2 >= 0) atomicAdd(&cnti[e2], 1);
    if (e3 >= 0) atomicAdd(&cnti[e3], 1);
  }
  __syncthreads();

  // inclusive prefix scan of cnti via wave shuffles
  {
    int val = (tid < NN) ? cnti[tid] : 0;
    #pragma unroll
    for (int o = 1; o < 64; o <<= 1) {
      int t = __shfl_up(val, o);
      if (ln >= o) val += t;
    }
    if (tid < NN && ln == 63) wsum[wv] = val;
    __syncthreads();
    if (tid < NN) {
      int offs = 0;
      #pragma unroll
      for (int w = 0; w < 4; ++w) if (w < wv) offs += wsum[w];
      scn[tid] = val + offs;
    }
  }
  __syncthreads();

  if (tid < NN) {
    #pragma unroll
    for (int k = 0; k < KK; ++k) {
      int d = nbr_s[tid*KK+k];
      if (d >= 0) {
        int pp2 = atomicAdd(&cur[d], 1);
        rev_s[scn[d] - cnti[d] + pp2] = tid;
      }
    }
  }
  __syncthreads();

  if (tid < NN) {
    int start = scn[tid] - cnti[tid];
    offs_go[(size_t)b*(NN+1) + tid] = start;
    if (tid == NN-1) offs_go[(size_t)b*(NN+1) + NN] = scn[NN-1];
    int cnt = cnti[tid];
    float r = 1.f / fmaxf((float)cnt, 1.f);
    ivd_o[(size_t)b*NN + tid] = cnt > 0 ? -r : r;   // sign encodes bf: neg -> bf=2
    reinterpret_cast<int4*>(rev_go)[(size_t)b*NN + tid] =
        *reinterpret_cast<int4*>(&rev_s[tid*KK]);
  }

  // ---------------- phase 2: ctx + af init ----------------
  {
    int s = tid >> 7, f = tid & 127;
    float v = hc1[((size_t)b*SS+s)*FSS + f];
    csf[s][f] = fmaxf((v - mu[f])*rstd[f]*gamma[f] + beta[f], 0.f);
  }
  __syncthreads();
  if (tid < 256) {
    int s = tid >> 6, f = tid & 63;
    float acc = 0.f;
    for (int c = 0; c < FSS; ++c) acc += csf[s][c] * w_s2a[c*FF+f];
    u_s[s][f] = acc;
  }
  __syncthreads();
  uint2* out2 = reinterpret_cast<uint2*>(af_o + gb);
  #pragma unroll
  for (int r = 0; r < 8; ++r) {
    int i4 = tid + r*512;
    int nn2 = i4 >> 4, c4 = (i4 & 15) * 4;
    float4 ax = axr[r];
    float4 ag = reinterpret_cast<const float4*>(assign_i)[(size_t)b*NN + nn2];
    float o0 = ax.x + b_s2a[c4+0] + ag.x*u_s[0][c4+0] + ag.y*u_s[1][c4+0] + ag.z*u_s[2][c4+0] + ag.w*u_s[3][c4+0];
    float o1 = ax.y + b_s2a[c4+1] + ag.x*u_s[0][c4+1] + ag.y*u_s[1][c4+1] + ag.z*u_s[2][c4+1] + ag.w*u_s[3][c4+1];
    float o2 = ax.z + b_s2a[c4+2] + ag.x*u_s[0][c4+2] + ag.y*u_s[1][c4+2] + ag.z*u_s[2][c4+2] + ag.w*u_s[3][c4+2];
    float o3 = ax.w + b_s2a[c4+3] + ag.x*u_s[0][c4+3] + ag.y*u_s[1][c4+3] + ag.z*u_s[2][c4+3] + ag.w*u_s[3][c4+3];
    uint2 pk; pk.x = pack2(o0, o1); pk.y = pack2(o2, o3);
    out2[i4] = pk;
  }
}

// ---------------------------------------------------------------- fine graph conv: bf16 MFMA, bf16 af
// 3 barriers; direct global store; packed coalesced stats. launch_bounds stays (512,4):
// (512,6) forces VGPR=40 -> spills the 32 live y-regs (R6/R7 lesson).
__global__ __launch_bounds__(512, 4) void k_fine3(
    unsigned short* __restrict__ af,
    const float* __restrict__ W, const float* __restrict__ bias,
    const float* __restrict__ pmu, const float* __restrict__ prstd,
    const float* __restrict__ pgamma, const float* __restrict__ pbeta, int applyBN,
    const int* __restrict__ rev_g, const int* __restrict__ offs_g,
    const float* __restrict__ ivd_g,
    float2* __restrict__ stp)
{
  const int b = blockIdx.x, tid = threadIdx.x;
  const int wv = tid >> 6, ln = tid & 63;
  const int l15 = ln & 15, g = ln >> 4;
  __shared__ __align__(16) unsigned short xb[NN*ROWB];
  __shared__ __align__(16) unsigned short wt[FF*ROWB];
  __shared__ __align__(16) int rev_s[NN*KK];             // overlaid by red1/red2 in epilogue
  __shared__ unsigned short offs_s[NN+1];
  __shared__ float ivd_s[NN];
  __shared__ float scale_s[FF], shift_s[FF];
  float* red1 = (float*)rev_s;
  float* red2 = red1 + 8*FF;

  if (tid < FF) {
    if (applyBN) {
      float sc = prstd[tid]*pgamma[tid];
      scale_s[tid] = sc; shift_s[tid] = pbeta[tid] - pmu[tid]*sc;
    } else { scale_s[tid] = 1.f; shift_s[tid] = 0.f; }
  }
  for (int i = tid; i < NN*KK; i += 512) rev_s[i] = rev_g[(size_t)b*NN*KK + i];
  if (tid <= NN) offs_s[tid] = (unsigned short)offs_g[(size_t)b*(NN+1) + tid];
  if (tid < NN) ivd_s[tid] = ivd_g[(size_t)b*NN + tid];

  {
    const int c = tid >> 3, f0 = (tid & 7) * 8;
    float4 w0 = *reinterpret_cast<const float4*>(&W[c*FF + f0]);
    float4 w1 = *reinterpret_cast<const float4*>(&W[c*FF + f0 + 4]);
    wt[(f0+0)*ROWB + c] = f2bf(w0.x);
    wt[(f0+1)*ROWB + c] = f2bf(w0.y);
    wt[(f0+2)*ROWB + c] = f2bf(w0.z);
    wt[(f0+3)*ROWB + c] = f2bf(w0.w);
    wt[(f0+4)*ROWB + c] = f2bf(w1.x);
    wt[(f0+5)*ROWB + c] = f2bf(w1.y);
    wt[(f0+6)*ROWB + c] = f2bf(w1.z);
    wt[(f0+7)*ROWB + c] = f2bf(w1.w);
  }

  unsigned short* afb = af + (size_t)b*NN*FF;
  const uint4* in8 = reinterpret_cast<const uint4*>(afb);
  __syncthreads();   // scale_s ready

  for (int i8 = tid; i8 < NN*FF/8; i8 += 512) {
    uint4 raw = in8[i8];
    int n = i8 >> 3, c8 = (i8 & 7) * 8;
    float v0 = bflo(raw.x), v1 = bfhi(raw.x), v2 = bflo(raw.y), v3 = bfhi(raw.y);
    float v4 = bflo(raw.z), v5 = bfhi(raw.z), v6 = bflo(raw.w), v7 = bfhi(raw.w);
    v0 = v0*scale_s[c8+0] + shift_s[c8+0];
    v1 = v1*scale_s[c8+1] + shift_s[c8+1];
    v2 = v2*scale_s[c8+2] + shift_s[c8+2];
    v3 = v3*scale_s[c8+3] + shift_s[c8+3];
    v4 = v4*scale_s[c8+4] + shift_s[c8+4];
    v5 = v5*scale_s[c8+5] + shift_s[c8+5];
    v6 = v6*scale_s[c8+6] + shift_s[c8+6];
    v7 = v7*scale_s[c8+7] + shift_s[c8+7];
    if (applyBN) {
      v0=fmaxf(v0,0.f); v1=fmaxf(v1,0.f); v2=fmaxf(v2,0.f); v3=fmaxf(v3,0.f);
      v4=fmaxf(v4,0.f); v5=fmaxf(v5,0.f); v6=fmaxf(v6,0.f); v7=fmaxf(v7,0.f);
    }
    uint4 pk;
    pk.x = pack2(v0, v1); pk.y = pack2(v2, v3);
    pk.z = pack2(v4, v5); pk.w = pack2(v6, v7);
    *reinterpret_cast<uint4*>(&xb[n*ROWB + c8]) = pk;
  }
  __syncthreads();   // barrier 2: xb fully staged

  const int nb = wv << 5;
#define GATH(J) float y##J; { const int n_ = nb + (J); \
    const int s0_ = offs_s[n_]; const int s1_ = offs_s[n_+1]; \
    float sum_ = 0.f; \
    for (int i_ = s0_; i_ < s1_; ++i_) sum_ += bf2f(xb[rev_s[i_]*ROWB + ln]); \
    y##J = bf2f(xb[n_*ROWB + ln]) + fabsf(ivd_s[n_])*sum_; }
  GATH(0)  GATH(1)  GATH(2)  GATH(3)  GATH(4)  GATH(5)  GATH(6)  GATH(7)
  GATH(8)  GATH(9)  GATH(10) GATH(11) GATH(12) GATH(13) GATH(14) GATH(15)
  GATH(16) GATH(17) GATH(18) GATH(19) GATH(20) GATH(21) GATH(22) GATH(23)
  GATH(24) GATH(25) GATH(26) GATH(27) GATH(28) GATH(29) GATH(30) GATH(31)
#undef GATH
  __syncthreads();   // barrier 3: gathers done; fences rev_s reads before red overlay
#define WRB(J) xb[(nb + (J))*ROWB + ln] = f2bf(y##J);
  WRB(0)  WRB(1)  WRB(2)  WRB(3)  WRB(4)  WRB(5)  WRB(6)  WRB(7)
  WRB(8)  WRB(9)  WRB(10) WRB(11) WRB(12) WRB(13) WRB(14) WRB(15)
  WRB(16) WRB(17) WRB(18) WRB(19) WRB(20) WRB(21) WRB(22) WRB(23)
  WRB(24) WRB(25) WRB(26) WRB(27) WRB(28) WRB(29) WRB(30) WRB(31)
#undef WRB
  // NO barrier: areg reads only the wave's own rows (intra-wave LDS RAW via lgkmcnt)

  short8 areg[2][2], breg[4][2];
  #pragma unroll
  for (int rt2 = 0; rt2 < 2; ++rt2)
    #pragma unroll
    for (int ks = 0; ks < 2; ++ks)
      areg[rt2][ks] = *reinterpret_cast<const short8*>(
          &xb[((2*wv+rt2)*16 + l15)*ROWB + ks*32 + g*8]);
  #pragma unroll
  for (int ct = 0; ct < 4; ++ct)
    #pragma unroll
    for (int ks = 0; ks < 2; ++ks)
      breg[ct][ks] = *reinterpret_cast<const short8*>(
          &wt[(ct*16 + l15)*ROWB + ks*32 + g*8]);

  f32x4 acc[2][4];
  #pragma unroll
  for (int rt2 = 0; rt2 < 2; ++rt2)
    #pragma unroll
    for (int ct = 0; ct < 4; ++ct)
      acc[rt2][ct] = (f32x4){0.f, 0.f, 0.f, 0.f};
  #pragma unroll
  for (int rt2 = 0; rt2 < 2; ++rt2)
    #pragma unroll
    for (int ct = 0; ct < 4; ++ct)
      #pragma unroll
      for (int ks = 0; ks < 2; ++ks)
        acc[rt2][ct] = __builtin_amdgcn_mfma_f32_16x16x32_bf16(
            areg[rt2][ks], breg[ct][ks], acc[rt2][ct], 0, 0, 0);

  float bias_c[4];
  #pragma unroll
  for (int ct = 0; ct < 4; ++ct) bias_c[ct] = bias[ct*16 + l15];
  float ps[4] = {0.f,0.f,0.f,0.f}, pss[4] = {0.f,0.f,0.f,0.f};
  #pragma unroll
  for (int rt2 = 0; rt2 < 2; ++rt2) {
    #pragma unroll
    for (int i = 0; i < 4; ++i) {
      int row = (2*wv+rt2)*16 + g*4 + i;
      float bfr = ivd_s[row] < 0.f ? 2.f : 1.f;
      #pragma unroll
      for (int ct = 0; ct < 4; ++ct) {
        float o = acc[rt2][ct][i] + bfr*bias_c[ct];
        afb[row*FF + ct*16 + l15] = f2bf(o);
        ps[ct] += o; pss[ct] += o*o;
      }
    }
  }
  #pragma unroll
  for (int ct = 0; ct < 4; ++ct) {
    float p = ps[ct], q = pss[ct];
    p += __shfl_xor(p, 16); p += __shfl_xor(p, 32);
    q += __shfl_xor(q, 16); q += __shfl_xor(q, 32);
    if (g == 0) { red1[wv*FF + ct*16 + l15] = p; red2[wv*FF + ct*16 + l15] = q; }
  }
  __syncthreads();   // final: red1/red2 complete

  if (tid < FF) {
    float s = 0.f, ss = 0.f;
    #pragma unroll
    for (int w = 0; w < 8; ++w) { s += red1[w*FF + tid]; ss += red2[w*FF + tid]; }
    stp[(size_t)b*FF + tid] = make_float2(s, ss);   // coalesced 512B/block
  }
}

// ---------------------------------------------------------------- pooling + output head (af = bf16, vectorized)
__global__ __launch_bounds__(256) void k_pool(
    const unsigned short* __restrict__ af, const float* __restrict__ pres,
    const float* __restrict__ pmu, const float* __restrict__ prstd,
    const float* __restrict__ pgamma, const float* __restrict__ pbeta,
    const float* __restrict__ w_out, const float* __restrict__ b_out,
    float* __restrict__ out)
{
  const int b = blockIdx.x, tid = threadIdx.x;
  const int wv = tid >> 6, ln = tid & 63;
  __shared__ float pr_s2[NN];
  __shared__ float red[FF][9];
  __shared__ float g_s[FF];
  __shared__ float prsum_s[4];
  float pw = pres[(size_t)b*NN + tid];
  pr_s2[tid] = pw;
  float t = pw;
  #pragma unroll
  for (int o = 32; o; o >>= 1) t += __shfl_xor(t, o);
  if (ln == 0) prsum_s[wv] = t;
  __syncthreads();

  const int c2 = (tid & 31) * 2, jrow = tid >> 5;
  float sc0 = prstd[c2+0]*pgamma[c2+0], sh0 = pbeta[c2+0] - pmu[c2+0]*sc0;
  float sc1 = prstd[c2+1]*pgamma[c2+1], sh1 = pbeta[c2+1] - pmu[c2+1]*sc1;
  float s0 = 0.f, s1 = 0.f;
  const unsigned* af2 = reinterpret_cast<const unsigned*>(af + (size_t)b*NN*FF);
  for (int n = jrow; n < NN; n += 8) {
    unsigned pk = af2[n*(FF/2) + (tid & 31)];
    float p = pr_s2[n];
    s0 += fmaxf(bflo(pk)*sc0 + sh0, 0.f) * p;
    s1 += fmaxf(bfhi(pk)*sc1 + sh1, 0.f) * p;
  }
  red[c2+0][jrow] = s0;
  red[c2+1][jrow] = s1;
  __syncthreads();
  if (tid < FF) {
    float s = 0.f;
    #pragma unroll
    for (int j = 0; j < 8; ++j) s += red[tid][j];
    float den = fmaxf(prsum_s[0]+prsum_s[1]+prsum_s[2]+prsum_s[3], 1e-8f);
    g_s[tid] = s / den;
  }
  __syncthreads();
  if (tid < OUTT) {
    float acc = b_out[tid];
    for (int f = 0; f < FF; ++f) acc += g_s[f] * w_out[f*OUTT + tid];
    out[(size_t)b*OUTT + tid] = acc;
  }
}

// ---------------------------------------------------------------- launch
extern "C" void kernel_launch(void* const* d_in, const int* in_sizes, int n_in,
                              void* d_out, int out_size, void* d_ws, size_t ws_size,
                              hipStream_t stream) {
  (void)in_sizes; (void)n_in; (void)out_size; (void)ws_size;
  const float* axle  = (const float*)d_in[0];
  const float* pos   = (const float*)d_in[1];
  const float* pres  = (const float*)d_in[2];
  const float* sq    = (const float*)d_in[3];
  const float* wq    = (const float*)d_in[4];
  const float* bq    = (const float*)d_in[5];
  const float* wk    = (const float*)d_in[6];
  const float* bk    = (const float*)d_in[7];
  const float* w_a2s = (const float*)d_in[8];
  const float* b_a2s = (const float*)d_in[9];
  const float* w_s2a = (const float*)d_in[10];
  const float* b_s2a = (const float*)d_in[11];
  const float* cW    = (const float*)d_in[12];
  const float* cb    = (const float*)d_in[13];
  const float* cg    = (const float*)d_in[14];
  const float* cbe   = (const float*)d_in[15];
  const float* fW    = (const float*)d_in[16];
  const float* fb    = (const float*)d_in[17];
  const float* fg    = (const float*)d_in[18];
  const float* fbe   = (const float*)d_in[19];
  const float* wout  = (const float*)d_in[20];
  const float* bout  = (const float*)d_in[21];
  float* out = (float*)d_out;

  char* base = (char*)d_ws;
  size_t off = 0;
  auto alloc = [&](size_t nbytes) -> void* {
    void* p = base + off; off += (nbytes + 255) & ~(size_t)255; return p;
  };
  unsigned short* af = (unsigned short*)alloc((size_t)BB*NN*FF*2);
  float* assign = (float*)alloc((size_t)BB*NN*SS*4);
  float* sf     = (float*)alloc((size_t)BB*SS*FSS*4);
  float* hc0    = (float*)alloc((size_t)BB*SS*FSS*4);
  float* hc1    = (float*)alloc((size_t)BB*SS*FSS*4);
  int*   rev    = (int*)  alloc((size_t)BB*NN*KK*4);
  int*   offs   = (int*)  alloc((size_t)BB*(NN+1)*4);
  float* ivd    = (float*)alloc((size_t)BB*NN*4);
  float2* stp   = (float2*)alloc((size_t)BB*FSS*8);
  float* mu0    = (float*)alloc(FSS*4);
  float* rs0    = (float*)alloc(FSS*4);
  float* mu1    = (float*)alloc(FSS*4);
  float* rs1    = (float*)alloc(FSS*4);
  float* muF    = (float*)alloc(FF*4);
  float* rsF    = (float*)alloc(FF*4);
  float* Vm     = (float*)alloc(FF*16*4);
  float* cv     = (float*)alloc(16*4);

  k_prep<<<1, 256, 0, stream>>>(sq, wq, bq, wk, bk, Vm, cv);
  k_attn_sf<<<BB, 256, 0, stream>>>(axle, Vm, cv, w_a2s, b_a2s, assign, sf);

  k_coarse<<<BB, 128, 0, stream>>>(sf,  cW,          cb,     mu0, rs0, cg, cbe, 0, hc0, stp);
  k_bnstats<<<FSS, 256, 0, stream>>>(stp, mu0, rs0, 1.f/((float)BB*SS), FSS);
  k_coarse<<<BB, 128, 0, stream>>>(hc0, cW+FSS*FSS,  cb+FSS, mu0, rs0, cg, cbe, 1, hc1, stp);
  k_bnstats<<<FSS, 256, 0, stream>>>(stp, mu1, rs1, 1.f/((float)BB*SS), FSS);

  k_knn_ctx<<<BB, 512, 0, stream>>>(pos, pres, axle, hc1, mu1, rs1, cg+FSS, cbe+FSS,
                                    assign, w_s2a, b_s2a, rev, offs, ivd, af);

  k_fine3<<<BB, 512, 0, stream>>>(af, fW,         fb,      muF, rsF, fg,    fbe,    0, rev, offs, ivd, stp);
  k_bnstats<<<FF, 256, 0, stream>>>(stp, muF, rsF, 1.f/((float)BB*NN), FF);
  k_fine3<<<BB, 512, 0, stream>>>(af, fW+FF*FF,   fb+FF,   muF, rsF, fg,    fbe,    1, rev, offs, ivd, stp);
  k_bnstats<<<FF, 256, 0, stream>>>(stp, muF, rsF, 1.f/((float)BB*NN), FF);
  k_fine3<<<BB, 512, 0, stream>>>(af, fW+2*FF*FF, fb+2*FF, muF, rsF, fg+FF, fbe+FF, 1, rev, offs, ivd, stp);
  k_bnstats<<<FF, 256, 0, stream>>>(stp, muF, rsF, 1.f/((float)BB*NN), FF);

  k_pool<<<BB, 256, 0, stream>>>(af, pres, muF, rsF, fg+2*FF, fbe+2*FF, wout, bout, out);
}

// Round 14
// 257.773 us; speedup vs baseline: 1.0185x; 1.0185x over previous
//
#include <hip/hip_runtime.h>
#include <hip/hip_bf16.h>
#include <math.h>

#define BB   1024
#define NN   256
#define FF   64
#define FSS  128
#define OUTT 128
#define SS   4
#define HH   4
#define KK   4
#define HDD  16
#define EPSF 1e-5f
#define BIGF 1000000000.0f
#define ROWB 72
#define ROWA 68

typedef __attribute__((ext_vector_type(8))) short short8;
typedef __attribute__((ext_vector_type(4))) float f32x4;

static __device__ __forceinline__ unsigned short f2bf(float f) {
  union { float f; unsigned u; } x; x.f = f;
  unsigned u = x.u + 0x7fffu + ((x.u >> 16) & 1u);   // RNE
  return (unsigned short)(u >> 16);
}
static __device__ __forceinline__ float bf2f(unsigned short h) {
  union { unsigned u; float f; } x; x.u = ((unsigned)h) << 16;
  return x.f;
}
static __device__ __forceinline__ float bflo(unsigned u) {
  union { unsigned u; float f; } x; x.u = u << 16; return x.f;
}
static __device__ __forceinline__ float bfhi(unsigned u) {
  union { unsigned u; float f; } x; x.u = u & 0xffff0000u; return x.f;
}
static __device__ __forceinline__ unsigned pack2(float a, float b) {
  return (unsigned)f2bf(a) | ((unsigned)f2bf(b) << 16);
}

// ---------------------------------------------------------------- k_prep: fold q through wk
__global__ __launch_bounds__(256) void k_prep(
    const float* __restrict__ sq, const float* __restrict__ wq, const float* __restrict__ bq,
    const float* __restrict__ wk, const float* __restrict__ bk,
    float* __restrict__ V_o, float* __restrict__ c_o)
{
  const int tid = threadIdx.x;
  __shared__ float sq_s[SS*FF];
  __shared__ float q_s[SS*FF];
  sq_s[tid] = sq[tid];
  __syncthreads();
  {
    int s = tid >> 6, f = tid & 63;
    float acc = bq[f];
    for (int c = 0; c < FF; ++c) acc += sq_s[s*FF+c] * wq[c*FF+f];
    q_s[s*FF+f] = acc;
  }
  __syncthreads();
  {
    int c = tid & 63, jb = (tid >> 6) * 4;
    for (int jj = 0; jj < 4; ++jj) {
      int j = jb + jj, h = j >> 2, s = j & 3;
      float acc = 0.f;
      for (int d = 0; d < HDD; ++d)
        acc += wk[c*FF + h*HDD + d] * q_s[s*FF + h*HDD + d];
      V_o[c*16 + j] = acc * 0.25f;
    }
  }
  if (tid < 16) {
    int h = tid >> 2, s = tid & 3;
    float acc = 0.f;
    for (int d = 0; d < HDD; ++d) acc += bk[h*HDD+d] * q_s[s*FF + h*HDD + d];
    c_o[tid] = acc * 0.25f;
  }
}

// ---------------------------------------------------------------- K1: attention + assign + sf
__global__ __launch_bounds__(256, 3) void k_attn_sf(
    const float* __restrict__ axle,
    const float* __restrict__ Vm, const float* __restrict__ cv,
    const float* __restrict__ w_a2s, const float* __restrict__ b_a2s,
    float* __restrict__ assign_o, float* __restrict__ sf_o)
{
  const int b = blockIdx.x, tid = threadIdx.x;
  const int wv = tid >> 6, ln = tid & 63;
  __shared__ __align__(16) unsigned short xb_a[NN*ROWA];
  __shared__ __align__(16) unsigned char u_buf[16*NN*2];
  __shared__ float mz_s[16][2];
  __hip_bfloat16* sc_s = (__hip_bfloat16*)u_buf;
  float (*as_s)[SS]    = (float (*)[SS])u_buf;
  float* t_s           = (float*)(u_buf + 4096);
  float* As_s          = (float*)(u_buf + 4096 + 1024);

  const float* afb = axle + (size_t)b*NN*FF;
  const float4* in4 = reinterpret_cast<const float4*>(afb);
  for (int i4 = tid; i4 < NN*FF/4; i4 += 256) {
    float4 v = in4[i4];
    int n = i4 >> 4, c4 = (i4 & 15) * 4;
    uint2 pk; pk.x = pack2(v.x, v.y); pk.y = pack2(v.z, v.w);
    *reinterpret_cast<uint2*>(&xb_a[n*ROWA + c4]) = pk;
  }
  __syncthreads();

  {
    float sc[16];
    #pragma unroll
    for (int j = 0; j < 16; ++j) sc[j] = cv[j];
    #pragma unroll
    for (int k = 0; k < 16; ++k) {
      uint2 pk = *reinterpret_cast<const uint2*>(&xb_a[tid*ROWA + 4*k]);
      float x0 = bflo(pk.x), x1 = bfhi(pk.x), x2 = bflo(pk.y), x3 = bfhi(pk.y);
      #pragma unroll
      for (int j = 0; j < 16; ++j) {
        float a = fmaf(x0, Vm[(4*k+0)*16+j], sc[j]);
        a = fmaf(x1, Vm[(4*k+1)*16+j], a);
        a = fmaf(x2, Vm[(4*k+2)*16+j], a);
        sc[j] = fmaf(x3, Vm[(4*k+3)*16+j], a);
      }
    }
    #pragma unroll
    for (int j = 0; j < 16; ++j) sc_s[j*NN + tid] = __float2bfloat16(sc[j]);
  }
  __syncthreads();

  for (int r = 0; r < 4; ++r) {
    int row = wv*4 + r;
    float v0 = __bfloat162float(sc_s[row*NN + ln]);
    float v1 = __bfloat162float(sc_s[row*NN + ln + 64]);
    float v2 = __bfloat162float(sc_s[row*NN + ln + 128]);
    float v3 = __bfloat162float(sc_s[row*NN + ln + 192]);
    float m = fmaxf(fmaxf(v0,v1), fmaxf(v2,v3));
    #pragma unroll
    for (int o = 32; o; o >>= 1) m = fmaxf(m, __shfl_xor(m, o));
    float z = __expf(v0-m) + __expf(v1-m) + __expf(v2-m) + __expf(v3-m);
    #pragma unroll
    for (int o = 32; o; o >>= 1) z += __shfl_xor(z, o);
    if (ln == 0) { mz_s[row][0] = m; mz_s[row][1] = 1.f/z; }
  }
  __syncthreads();

  float4 av;
  {
    float at0 = 0.f, at1 = 0.f, at2 = 0.f, at3 = 0.f;
    #pragma unroll
    for (int h = 0; h < HH; ++h) {
      at0 += __expf(__bfloat162float(sc_s[(h*4+0)*NN + tid]) - mz_s[h*4+0][0]) * mz_s[h*4+0][1];
      at1 += __expf(__bfloat162float(sc_s[(h*4+1)*NN + tid]) - mz_s[h*4+1][0]) * mz_s[h*4+1][1];
      at2 += __expf(__bfloat162float(sc_s[(h*4+2)*NN + tid]) - mz_s[h*4+2][0]) * mz_s[h*4+2][1];
      at3 += __expf(__bfloat162float(sc_s[(h*4+3)*NN + tid]) - mz_s[h*4+3][0]) * mz_s[h*4+3][1];
    }
    at0 *= 0.25f; at1 *= 0.25f; at2 *= 0.25f; at3 *= 0.25f;
    float m = fmaxf(fmaxf(at0,at1), fmaxf(at2,at3));
    float e0=__expf(at0-m), e1=__expf(at1-m), e2=__expf(at2-m), e3=__expf(at3-m);
    float zi = 1.f/(e0+e1+e2+e3);
    av = make_float4(e0*zi, e1*zi, e2*zi, e3*zi);
    reinterpret_cast<float4*>(assign_o)[(size_t)b*NN + tid] = av;
  }
  __syncthreads();
  *reinterpret_cast<float4*>(&as_s[tid][0]) = av;
  __syncthreads();

  {
    int s = wv, half = ln >> 5, c2 = ln & 31;
    float t0 = 0.f, t1 = 0.f, aa = 0.f;
    int n0 = half * 128;
    for (int n = n0; n < n0 + 128; ++n) {
      float a = as_s[n][s];
      unsigned pk = *reinterpret_cast<const unsigned*>(&xb_a[n*ROWA + 2*c2]);
      t0 = fmaf(a, bflo(pk), t0);
      t1 = fmaf(a, bfhi(pk), t1);
      aa += a;
    }
    t0 += __shfl_xor(t0, 32);
    t1 += __shfl_xor(t1, 32);
    aa += __shfl_xor(aa, 32);
    if (half == 0) {
      t_s[s*FF + 2*c2]     = t0;
      t_s[s*FF + 2*c2 + 1] = t1;
      if (c2 == 0) As_s[s] = aa;
    }
  }
  __syncthreads();

  for (int o = tid; o < SS*FSS; o += 256) {
    int s = o >> 7, f = o & 127;
    float acc = As_s[s] * b_a2s[f];
    for (int c = 0; c < FF; ++c) acc += t_s[s*FF + c] * w_a2s[c*FSS+f];
    sf_o[((size_t)b*SS+s)*FSS+f] = acc;
  }
}

// ---------------------------------------------------------------- coarse graph conv (packed coalesced stats)
__global__ __launch_bounds__(128) void k_coarse(
    const float* __restrict__ in, const float* __restrict__ W, const float* __restrict__ bias,
    const float* __restrict__ pmu, const float* __restrict__ prstd,
    const float* __restrict__ pgamma, const float* __restrict__ pbeta, int applyBN,
    float* __restrict__ out, float2* __restrict__ stp)
{
  const int b = blockIdx.x, f = threadIdx.x;
  __shared__ float x_s[SS][FSS];
  #pragma unroll
  for (int i = 0; i < SS; ++i) {
    float v = in[((size_t)b*SS+i)*FSS + f];
    if (applyBN) v = fmaxf((v - pmu[f])*prstd[f]*pgamma[f] + pbeta[f], 0.f);
    x_s[i][f] = v;
  }
  __syncthreads();
  float h0 = bias[f], h1 = h0, h2 = h0, h3 = h0;
  for (int c = 0; c < FSS; ++c) {
    float w = W[c*FSS+f];
    h0 += x_s[0][c]*w; h1 += x_s[1][c]*w; h2 += x_s[2][c]*w; h3 += x_s[3][c]*w;
  }
  float s4 = h0+h1+h2+h3;
  const float inv3 = 1.f/3.f;
  float o0 = h0 + (s4-h0)*inv3;
  float o1 = h1 + (s4-h1)*inv3;
  float o2 = h2 + (s4-h2)*inv3;
  float o3 = h3 + (s4-h3)*inv3;
  size_t ob = (size_t)b*SS*FSS + f;
  out[ob] = o0; out[ob+FSS] = o1; out[ob+2*FSS] = o2; out[ob+3*FSS] = o3;
  stp[(size_t)b*FSS + f] = make_float2(o0+o1+o2+o3, o0*o0+o1*o1+o2*o2+o3*o3);
}

// ---------------------------------------------------------------- BN stats reduce (transposed packed reads)
__global__ __launch_bounds__(256) void k_bnstats(
    const float2* __restrict__ sp, float* __restrict__ mu, float* __restrict__ rstd,
    float invcnt, int F)
{
  const int f = blockIdx.x, tid = threadIdx.x;
  float a = 0.f, q = 0.f;
  for (int j = tid; j < BB; j += 256) {
    float2 v = sp[(size_t)j*F + f];
    a += v.x; q += v.y;
  }
  #pragma unroll
  for (int o = 32; o; o >>= 1) { a += __shfl_xor(a, o); q += __shfl_xor(q, o); }
  __shared__ float ra[4], rq[4];
  int wv = tid >> 6;
  if ((tid & 63) == 0) { ra[wv] = a; rq[wv] = q; }
  __syncthreads();
  if (tid == 0) {
    float s = ra[0]+ra[1]+ra[2]+ra[3], ss = rq[0]+rq[1]+rq[2]+rq[3];
    float m = s*invcnt; float v = ss*invcnt - m*m;
    mu[f] = m; rstd[f] = 1.f / sqrtf(v + EPSF);
  }
}

// ---------------------------------------------------------------- fused kNN + ctx (512 threads)
// R12 form: NO axle prefetch (R13's 32-VGPR prefetch dropped occupancy 56->46 and
// VALUBusy 86->78 on the throughput-bound scan: -4us). ctx reads axle in phase 2.
__global__ __launch_bounds__(512) void k_knn_ctx(
    const float* __restrict__ pos, const float* __restrict__ pres,
    const float* __restrict__ axle, const float* __restrict__ hc1,
    const float* __restrict__ mu, const float* __restrict__ rstd,
    const float* __restrict__ gamma, const float* __restrict__ beta,
    const float* __restrict__ assign_i,
    const float* __restrict__ w_s2a, const float* __restrict__ b_s2a,
    int* __restrict__ rev_go, int* __restrict__ offs_go,
    float* __restrict__ ivd_o, unsigned short* __restrict__ af_o)
{
  const int b = blockIdx.x, tid = threadIdx.x;
  const int ln = tid & 63, wv = tid >> 6;
  const int n = tid >> 1, half = tid & 1;
  __shared__ float2 pp[NN];
  __shared__ int vld[NN];
  __shared__ int wcnt[4];
  __shared__ int wsum[4];
  __shared__ int nbr_s[NN*KK];
  __shared__ int cnti[NN], scn[NN], cur[NN];
  __shared__ __align__(16) int rev_s[NN*KK];
  __shared__ float csf[SS][FSS];
  __shared__ float u_s[SS][FF];

  // ---------------- phase 1: kNN ----------------
  if (tid < NN) {
    float2 p = reinterpret_cast<const float2*>(pos)[(size_t)b*NN + tid];
    float pr = pres[(size_t)b*NN + tid];
    int v = pr > 0.5f ? 1 : 0;
    vld[tid] = v;
    pp[tid] = v ? p : make_float2(3.4e38f, 3.4e38f);
    cnti[tid] = 0; cur[tid] = 0;
    reinterpret_cast<int4*>(rev_s)[tid] = make_int4(0,0,0,0);
    int cnt = v;
    #pragma unroll
    for (int o = 32; o; o >>= 1) cnt += __shfl_xor(cnt, o);
    if (ln == 0) wcnt[wv] = cnt;
  }
  __syncthreads();
  const int nv = wcnt[0]+wcnt[1]+wcnt[2]+wcnt[3];

  float2 sp = pp[n];
  const float xi = sp.x, yi = sp.y;
  float b0=3.4e38f, b1=b0, b2=b0, b3=b0, b4=b0;
  int   j0=0, j1=0, j2=0, j3=0, j4=0;
  const int jb = half << 7;
  for (int j = jb; j < jb + 128; ++j) {
    float2 q = pp[j];
    float dx = __fsub_rn(xi, q.x);
    float dy = __fsub_rn(yi, q.y);
    float d2 = __fadd_rn(__fmul_rn(dx,dx), __fmul_rn(dy,dy)); // no fma: match numpy
    if (d2 < b4) {
      b4 = d2; j4 = j;
      if (b4 < b3) { float t=b3; b3=b4; b4=t; int ti=j3; j3=j4; j4=ti; }
      if (b3 < b2) { float t=b2; b2=b3; b3=t; int ti=j2; j2=j3; j3=ti; }
      if (b2 < b1) { float t=b1; b1=b2; b2=t; int ti=j1; j1=j2; j2=ti; }
      if (b1 < b0) { float t=b0; b0=b1; b1=t; int ti=j0; j0=j1; j1=ti; }
    }
  }
  float c0 = __shfl_xor(b0,1), c1 = __shfl_xor(b1,1), c2 = __shfl_xor(b2,1),
        c3 = __shfl_xor(b3,1), c4 = __shfl_xor(b4,1);
  int   k0 = __shfl_xor(j0,1), k1 = __shfl_xor(j1,1), k2 = __shfl_xor(j2,1),
        k3 = __shfl_xor(j3,1), k4 = __shfl_xor(j4,1);

  if (half == 0) {
#define MSTEP(OD, OJ) do { bool ta = (b0 <= c0); \
    OD = ta ? b0 : c0; OJ = ta ? j0 : k0; \
    b0 = ta ? b1 : b0; j0 = ta ? j1 : j0; \
    b1 = ta ? b2 : b1; j1 = ta ? j2 : j1; \
    b2 = ta ? b3 : b2; j2 = ta ? j3 : j2; \
    b3 = ta ? b4 : b3; j3 = ta ? j4 : j3; \
    b4 = ta ? 3.4e38f : b4; \
    c0 = ta ? c0 : c1; k0 = ta ? k0 : k1; \
    c1 = ta ? c1 : c2; k1 = ta ? k1 : k2; \
    c2 = ta ? c2 : c3; k2 = ta ? k2 : k3; \
    c3 = ta ? c3 : c4; k3 = ta ? k3 : k4; \
    c4 = ta ? c4 : 3.4e38f; } while(0)
    float m0d, dd1, dd2, dd3, dd4; int m0j, i1, i2, i3, i4;
    MSTEP(m0d, m0j);
    MSTEP(dd1, i1); MSTEP(dd2, i2); MSTEP(dd3, i3); MSTEP(dd4, i4);
#undef MSTEP
    (void)m0d; (void)m0j;
    bool okrow = (vld[n] != 0) && (nv >= 2);
    int e0 = (okrow && dd1 < 0.5f*BIGF) ? i1 : -1;
    int e1 = (okrow && dd2 < 0.5f*BIGF) ? i2 : -1;
    int e2 = (okrow && dd3 < 0.5f*BIGF) ? i3 : -1;
    int e3 = (okrow && dd4 < 0.5f*BIGF) ? i4 : -1;
    nbr_s[n*KK+0] = e0; nbr_s[n*KK+1] = e1;
    nbr_s[n*KK+2] = e2; nbr_s[n*KK+3] = e3;
    if (e0 >= 0) atomicAdd(&cnti[e0], 1);
    if (e1 >= 0) atomicAdd(&cnti[e1], 1);
    if (e2 >= 0) atomicAdd(&cnti[e2], 1);
    if (e3 >= 0) atomicAdd(&cnti[e3], 1);
  }
  __syncthreads();

  // inclusive prefix scan of cnti via wave shuffles
  {
    int val = (tid < NN) ? cnti[tid] : 0;
    #pragma unroll
    for (int o = 1; o < 64; o <<= 1) {
      int t = __shfl_up(val, o);
      if (ln >= o) val += t;
    }
    if (tid < NN && ln == 63) wsum[wv] = val;
    __syncthreads();
    if (tid < NN) {
      int offs = 0;
      #pragma unroll
      for (int w = 0; w < 4; ++w) if (w < wv) offs += wsum[w];
      scn[tid] = val + offs;
    }
  }
  __syncthreads();

  if (tid < NN) {
    #pragma unroll
    for (int k = 0; k < KK; ++k) {
      int d = nbr_s[tid*KK+k];
      if (d >= 0) {
        int pp2 = atomicAdd(&cur[d], 1);
        rev_s[scn[d] - cnti[d] + pp2] = tid;
      }
    }
  }
  __syncthreads();

  if (tid < NN) {
    int start = scn[tid] - cnti[tid];
    offs_go[(size_t)b*(NN+1) + tid] = start;
    if (tid == NN-1) offs_go[(size_t)b*(NN+1) + NN] = scn[NN-1];
    int cnt = cnti[tid];
    float r = 1.f / fmaxf((float)cnt, 1.f);
    ivd_o[(size_t)b*NN + tid] = cnt > 0 ? -r : r;   // sign encodes bf: neg -> bf=2
    reinterpret_cast<int4*>(rev_go)[(size_t)b*NN + tid] =
        *reinterpret_cast<int4*>(&rev_s[tid*KK]);
  }

  // ---------------- phase 2: ctx + af init ----------------
  {
    int s = tid >> 7, f = tid & 127;
    float v = hc1[((size_t)b*SS+s)*FSS + f];
    csf[s][f] = fmaxf((v - mu[f])*rstd[f]*gamma[f] + beta[f], 0.f);
  }
  __syncthreads();
  if (tid < 256) {
    int s = tid >> 6, f = tid & 63;
    float acc = 0.f;
    for (int c = 0; c < FSS; ++c) acc += csf[s][c] * w_s2a[c*FF+f];
    u_s[s][f] = acc;
  }
  __syncthreads();
  const size_t gb = (size_t)b*NN*FF;
  const float4* ax4 = reinterpret_cast<const float4*>(axle + gb);
  uint2* out2 = reinterpret_cast<uint2*>(af_o + gb);
  for (int i4 = tid; i4 < NN*FF/4; i4 += 512) {
    int nn2 = i4 >> 4, c4 = (i4 & 15) * 4;
    float4 ax = ax4[i4];
    float4 ag = reinterpret_cast<const float4*>(assign_i)[(size_t)b*NN + nn2];
    float o0 = ax.x + b_s2a[c4+0] + ag.x*u_s[0][c4+0] + ag.y*u_s[1][c4+0] + ag.z*u_s[2][c4+0] + ag.w*u_s[3][c4+0];
    float o1 = ax.y + b_s2a[c4+1] + ag.x*u_s[0][c4+1] + ag.y*u_s[1][c4+1] + ag.z*u_s[2][c4+1] + ag.w*u_s[3][c4+1];
    float o2 = ax.z + b_s2a[c4+2] + ag.x*u_s[0][c4+2] + ag.y*u_s[1][c4+2] + ag.z*u_s[2][c4+2] + ag.w*u_s[3][c4+2];
    float o3 = ax.w + b_s2a[c4+3] + ag.x*u_s[0][c4+3] + ag.y*u_s[1][c4+3] + ag.z*u_s[2][c4+3] + ag.w*u_s[3][c4+3];
    uint2 pk; pk.x = pack2(o0, o1); pk.y = pack2(o2, o3);
    out2[i4] = pk;
  }
}

// ---------------------------------------------------------------- fine graph conv: bf16 MFMA, bf16 af
// 3 barriers; direct global store; packed coalesced stats. launch_bounds stays (512,4):
// (512,6) forces VGPR=40 -> spills the 32 live y-regs (R6/R7 lesson).
__global__ __launch_bounds__(512, 4) void k_fine3(
    unsigned short* __restrict__ af,
    const float* __restrict__ W, const float* __restrict__ bias,
    const float* __restrict__ pmu, const float* __restrict__ prstd,
    const float* __restrict__ pgamma, const float* __restrict__ pbeta, int applyBN,
    const int* __restrict__ rev_g, const int* __restrict__ offs_g,
    const float* __restrict__ ivd_g,
    float2* __restrict__ stp)
{
  const int b = blockIdx.x, tid = threadIdx.x;
  const int wv = tid >> 6, ln = tid & 63;
  const int l15 = ln & 15, g = ln >> 4;
  __shared__ __align__(16) unsigned short xb[NN*ROWB];
  __shared__ __align__(16) unsigned short wt[FF*ROWB];
  __shared__ __align__(16) int rev_s[NN*KK];             // overlaid by red1/red2 in epilogue
  __shared__ unsigned short offs_s[NN+1];
  __shared__ float ivd_s[NN];
  __shared__ float scale_s[FF], shift_s[FF];
  float* red1 = (float*)rev_s;
  float* red2 = red1 + 8*FF;

  if (tid < FF) {
    if (applyBN) {
      float sc = prstd[tid]*pgamma[tid];
      scale_s[tid] = sc; shift_s[tid] = pbeta[tid] - pmu[tid]*sc;
    } else { scale_s[tid] = 1.f; shift_s[tid] = 0.f; }
  }
  for (int i = tid; i < NN*KK; i += 512) rev_s[i] = rev_g[(size_t)b*NN*KK + i];
  if (tid <= NN) offs_s[tid] = (unsigned short)offs_g[(size_t)b*(NN+1) + tid];
  if (tid < NN) ivd_s[tid] = ivd_g[(size_t)b*NN + tid];

  {
    const int c = tid >> 3, f0 = (tid & 7) * 8;
    float4 w0 = *reinterpret_cast<const float4*>(&W[c*FF + f0]);
    float4 w1 = *reinterpret_cast<const float4*>(&W[c*FF + f0 + 4]);
    wt[(f0+0)*ROWB + c] = f2bf(w0.x);
    wt[(f0+1)*ROWB + c] = f2bf(w0.y);
    wt[(f0+2)*ROWB + c] = f2bf(w0.z);
    wt[(f0+3)*ROWB + c] = f2bf(w0.w);
    wt[(f0+4)*ROWB + c] = f2bf(w1.x);
    wt[(f0+5)*ROWB + c] = f2bf(w1.y);
    wt[(f0+6)*ROWB + c] = f2bf(w1.z);
    wt[(f0+7)*ROWB + c] = f2bf(w1.w);
  }

  unsigned short* afb = af + (size_t)b*NN*FF;
  const uint4* in8 = reinterpret_cast<const uint4*>(afb);
  __syncthreads();   // scale_s ready

  for (int i8 = tid; i8 < NN*FF/8; i8 += 512) {
    uint4 raw = in8[i8];
    int n = i8 >> 3, c8 = (i8 & 7) * 8;
    float v0 = bflo(raw.x), v1 = bfhi(raw.x), v2 = bflo(raw.y), v3 = bfhi(raw.y);
    float v4 = bflo(raw.z), v5 = bfhi(raw.z), v6 = bflo(raw.w), v7 = bfhi(raw.w);
    v0 = v0*scale_s[c8+0] + shift_s[c8+0];
    v1 = v1*scale_s[c8+1] + shift_s[c8+1];
    v2 = v2*scale_s[c8+2] + shift_s[c8+2];
    v3 = v3*scale_s[c8+3] + shift_s[c8+3];
    v4 = v4*scale_s[c8+4] + shift_s[c8+4];
    v5 = v5*scale_s[c8+5] + shift_s[c8+5];
    v6 = v6*scale_s[c8+6] + shift_s[c8+6];
    v7 = v7*scale_s[c8+7] + shift_s[c8+7];
    if (applyBN) {
      v0=fmaxf(v0,0.f); v1=fmaxf(v1,0.f); v2=fmaxf(v2,0.f); v3=fmaxf(v3,0.f);
      v4=fmaxf(v4,0.f); v5=fmaxf(v5,0.f); v6=fmaxf(v6,0.f); v7=fmaxf(v7,0.f);
    }
    uint4 pk;
    pk.x = pack2(v0, v1); pk.y = pack2(v2, v3);
    pk.z = pack2(v4, v5); pk.w = pack2(v6, v7);
    *reinterpret_cast<uint4*>(&xb[n*ROWB + c8]) = pk;
  }
  __syncthreads();   // barrier 2: xb fully staged

  const int nb = wv << 5;
#define GATH(J) float y##J; { const int n_ = nb + (J); \
    const int s0_ = offs_s[n_]; const int s1_ = offs_s[n_+1]; \
    float sum_ = 0.f; \
    for (int i_ = s0_; i_ < s1_; ++i_) sum_ += bf2f(xb[rev_s[i_]*ROWB + ln]); \
    y##J = bf2f(xb[n_*ROWB + ln]) + fabsf(ivd_s[n_])*sum_; }
  GATH(0)  GATH(1)  GATH(2)  GATH(3)  GATH(4)  GATH(5)  GATH(6)  GATH(7)
  GATH(8)  GATH(9)  GATH(10) GATH(11) GATH(12) GATH(13) GATH(14) GATH(15)
  GATH(16) GATH(17) GATH(18) GATH(19) GATH(20) GATH(21) GATH(22) GATH(23)
  GATH(24) GATH(25) GATH(26) GATH(27) GATH(28) GATH(29) GATH(30) GATH(31)
#undef GATH
  __syncthreads();   // barrier 3: gathers done; fences rev_s reads before red overlay
#define WRB(J) xb[(nb + (J))*ROWB + ln] = f2bf(y##J);
  WRB(0)  WRB(1)  WRB(2)  WRB(3)  WRB(4)  WRB(5)  WRB(6)  WRB(7)
  WRB(8)  WRB(9)  WRB(10) WRB(11) WRB(12) WRB(13) WRB(14) WRB(15)
  WRB(16) WRB(17) WRB(18) WRB(19) WRB(20) WRB(21) WRB(22) WRB(23)
  WRB(24) WRB(25) WRB(26) WRB(27) WRB(28) WRB(29) WRB(30) WRB(31)
#undef WRB
  // NO barrier: areg reads only the wave's own rows (intra-wave LDS RAW via lgkmcnt)

  short8 areg[2][2], breg[4][2];
  #pragma unroll
  for (int rt2 = 0; rt2 < 2; ++rt2)
    #pragma unroll
    for (int ks = 0; ks < 2; ++ks)
      areg[rt2][ks] = *reinterpret_cast<const short8*>(
          &xb[((2*wv+rt2)*16 + l15)*ROWB + ks*32 + g*8]);
  #pragma unroll
  for (int ct = 0; ct < 4; ++ct)
    #pragma unroll
    for (int ks = 0; ks < 2; ++ks)
      breg[ct][ks] = *reinterpret_cast<const short8*>(
          &wt[(ct*16 + l15)*ROWB + ks*32 + g*8]);

  f32x4 acc[2][4];
  #pragma unroll
  for (int rt2 = 0; rt2 < 2; ++rt2)
    #pragma unroll
    for (int ct = 0; ct < 4; ++ct)
      acc[rt2][ct] = (f32x4){0.f, 0.f, 0.f, 0.f};
  #pragma unroll
  for (int rt2 = 0; rt2 < 2; ++rt2)
    #pragma unroll
    for (int ct = 0; ct < 4; ++ct)
      #pragma unroll
      for (int ks = 0; ks < 2; ++ks)
        acc[rt2][ct] = __builtin_amdgcn_mfma_f32_16x16x32_bf16(
            areg[rt2][ks], breg[ct][ks], acc[rt2][ct], 0, 0, 0);

  float bias_c[4];
  #pragma unroll
  for (int ct = 0; ct < 4; ++ct) bias_c[ct] = bias[ct*16 + l15];
  float ps[4] = {0.f,0.f,0.f,0.f}, pss[4] = {0.f,0.f,0.f,0.f};
  #pragma unroll
  for (int rt2 = 0; rt2 < 2; ++rt2) {
    #pragma unroll
    for (int i = 0; i < 4; ++i) {
      int row = (2*wv+rt2)*16 + g*4 + i;
      float bfr = ivd_s[row] < 0.f ? 2.f : 1.f;
      #pragma unroll
      for (int ct = 0; ct < 4; ++ct) {
        float o = acc[rt2][ct][i] + bfr*bias_c[ct];
        afb[row*FF + ct*16 + l15] = f2bf(o);
        ps[ct] += o; pss[ct] += o*o;
      }
    }
  }
  #pragma unroll
  for (int ct = 0; ct < 4; ++ct) {
    float p = ps[ct], q = pss[ct];
    p += __shfl_xor(p, 16); p += __shfl_xor(p, 32);
    q += __shfl_xor(q, 16); q += __shfl_xor(q, 32);
    if (g == 0) { red1[wv*FF + ct*16 + l15] = p; red2[wv*FF + ct*16 + l15] = q; }
  }
  __syncthreads();   // final: red1/red2 complete

  if (tid < FF) {
    float s = 0.f, ss = 0.f;
    #pragma unroll
    for (int w = 0; w < 8; ++w) { s += red1[w*FF + tid]; ss += red2[w*FF + tid]; }
    stp[(size_t)b*FF + tid] = make_float2(s, ss);   // coalesced 512B/block
  }
}

// ---------------------------------------------------------------- pooling + output head (af = bf16, vectorized)
__global__ __launch_bounds__(256) void k_pool(
    const unsigned short* __restrict__ af, const float* __restrict__ pres,
    const float* __restrict__ pmu, const float* __restrict__ prstd,
    const float* __restrict__ pgamma, const float* __restrict__ pbeta,
    const float* __restrict__ w_out, const float* __restrict__ b_out,
    float* __restrict__ out)
{
  const int b = blockIdx.x, tid = threadIdx.x;
  const int wv = tid >> 6, ln = tid & 63;
  __shared__ float pr_s2[NN];
  __shared__ float red[FF][9];
  __shared__ float g_s[FF];
  __shared__ float prsum_s[4];
  float pw = pres[(size_t)b*NN + tid];
  pr_s2[tid] = pw;
  float t = pw;
  #pragma unroll
  for (int o = 32; o; o >>= 1) t += __shfl_xor(t, o);
  if (ln == 0) prsum_s[wv] = t;
  __syncthreads();

  const int c2 = (tid & 31) * 2, jrow = tid >> 5;
  float sc0 = prstd[c2+0]*pgamma[c2+0], sh0 = pbeta[c2+0] - pmu[c2+0]*sc0;
  float sc1 = prstd[c2+1]*pgamma[c2+1], sh1 = pbeta[c2+1] - pmu[c2+1]*sc1;
  float s0 = 0.f, s1 = 0.f;
  const unsigned* af2 = reinterpret_cast<const unsigned*>(af + (size_t)b*NN*FF);
  for (int n = jrow; n < NN; n += 8) {
    unsigned pk = af2[n*(FF/2) + (tid & 31)];
    float p = pr_s2[n];
    s0 += fmaxf(bflo(pk)*sc0 + sh0, 0.f) * p;
    s1 += fmaxf(bfhi(pk)*sc1 + sh1, 0.f) * p;
  }
  red[c2+0][jrow] = s0;
  red[c2+1][jrow] = s1;
  __syncthreads();
  if (tid < FF) {
    float s = 0.f;
    #pragma unroll
    for (int j = 0; j < 8; ++j) s += red[tid][j];
    float den = fmaxf(prsum_s[0]+prsum_s[1]+prsum_s[2]+prsum_s[3], 1e-8f);
    g_s[tid] = s / den;
  }
  __syncthreads();
  if (tid < OUTT) {
    float acc = b_out[tid];
    for (int f = 0; f < FF; ++f) acc += g_s[f] * w_out[f*OUTT + tid];
    out[(size_t)b*OUTT + tid] = acc;
  }
}

// ---------------------------------------------------------------- launch
extern "C" void kernel_launch(void* const* d_in, const int* in_sizes, int n_in,
                              void* d_out, int out_size, void* d_ws, size_t ws_size,
                              hipStream_t stream) {
  (void)in_sizes; (void)n_in; (void)out_size; (void)ws_size;
  const float* axle  = (const float*)d_in[0];
  const float* pos   = (const float*)d_in[1];
  const float* pres  = (const float*)d_in[2];
  const float* sq    = (const float*)d_in[3];
  const float* wq    = (const float*)d_in[4];
  const float* bq    = (const float*)d_in[5];
  const float* wk    = (const float*)d_in[6];
  const float* bk    = (const float*)d_in[7];
  const float* w_a2s = (const float*)d_in[8];
  const float* b_a2s = (const float*)d_in[9];
  const float* w_s2a = (const float*)d_in[10];
  const float* b_s2a = (const float*)d_in[11];
  const float* cW    = (const float*)d_in[12];
  const float* cb    = (const float*)d_in[13];
  const float* cg    = (const float*)d_in[14];
  const float* cbe   = (const float*)d_in[15];
  const float* fW    = (const float*)d_in[16];
  const float* fb    = (const float*)d_in[17];
  const float* fg    = (const float*)d_in[18];
  const float* fbe   = (const float*)d_in[19];
  const float* wout  = (const float*)d_in[20];
  const float* bout  = (const float*)d_in[21];
  float* out = (float*)d_out;

  char* base = (char*)d_ws;
  size_t off = 0;
  auto alloc = [&](size_t nbytes) -> void* {
    void* p = base + off; off += (nbytes + 255) & ~(size_t)255; return p;
  };
  unsigned short* af = (unsigned short*)alloc((size_t)BB*NN*FF*2);
  float* assign = (float*)alloc((size_t)BB*NN*SS*4);
  float* sf     = (float*)alloc((size_t)BB*SS*FSS*4);
  float* hc0    = (float*)alloc((size_t)BB*SS*FSS*4);
  float* hc1    = (float*)alloc((size_t)BB*SS*FSS*4);
  int*   rev    = (int*)  alloc((size_t)BB*NN*KK*4);
  int*   offs   = (int*)  alloc((size_t)BB*(NN+1)*4);
  float* ivd    = (float*)alloc((size_t)BB*NN*4);
  float2* stp   = (float2*)alloc((size_t)BB*FSS*8);
  float* mu0    = (float*)alloc(FSS*4);
  float* rs0    = (float*)alloc(FSS*4);
  float* mu1    = (float*)alloc(FSS*4);
  float* rs1    = (float*)alloc(FSS*4);
  float* muF    = (float*)alloc(FF*4);
  float* rsF    = (float*)alloc(FF*4);
  float* Vm     = (float*)alloc(FF*16*4);
  float* cv     = (float*)alloc(16*4);

  k_prep<<<1, 256, 0, stream>>>(sq, wq, bq, wk, bk, Vm, cv);
  k_attn_sf<<<BB, 256, 0, stream>>>(axle, Vm, cv, w_a2s, b_a2s, assign, sf);

  k_coarse<<<BB, 128, 0, stream>>>(sf,  cW,          cb,     mu0, rs0, cg, cbe, 0, hc0, stp);
  k_bnstats<<<FSS, 256, 0, stream>>>(stp, mu0, rs0, 1.f/((float)BB*SS), FSS);
  k_coarse<<<BB, 128, 0, stream>>>(hc0, cW+FSS*FSS,  cb+FSS, mu0, rs0, cg, cbe, 1, hc1, stp);
  k_bnstats<<<FSS, 256, 0, stream>>>(stp, mu1, rs1, 1.f/((float)BB*SS), FSS);

  k_knn_ctx<<<BB, 512, 0, stream>>>(pos, pres, axle, hc1, mu1, rs1, cg+FSS, cbe+FSS,
                                    assign, w_s2a, b_s2a, rev, offs, ivd, af);

  k_fine3<<<BB, 512, 0, stream>>>(af, fW,         fb,      muF, rsF, fg,    fbe,    0, rev, offs, ivd, stp);
  k_bnstats<<<FF, 256, 0, stream>>>(stp, muF, rsF, 1.f/((float)BB*NN), FF);
  k_fine3<<<BB, 512, 0, stream>>>(af, fW+FF*FF,   fb+FF,   muF, rsF, fg,    fbe,    1, rev, offs, ivd, stp);
  k_bnstats<<<FF, 256, 0, stream>>>(stp, muF, rsF, 1.f/((float)BB*NN), FF);
  k_fine3<<<BB, 512, 0, stream>>>(af, fW+2*FF*FF, fb+2*FF, muF, rsF, fg+FF, fbe+FF, 1, rev, offs, ivd, stp);
  k_bnstats<<<FF, 256, 0, stream>>>(stp, muF, rsF, 1.f/((float)BB*NN), FF);

  k_pool<<<BB, 256, 0, stream>>>(af, pres, muF, rsF, fg+2*FF, fbe+2*FF, wout, bout, out);
}